// Round 24
// baseline (456.888 us; speedup 1.0000x reference)
//
#include <hip/hip_runtime.h>

typedef int v4i __attribute__((ext_vector_type(4)));
typedef float f32x4 __attribute__((ext_vector_type(4)));

static constexpr int K_DIM = 4096;
static constexpr int BM = 128, BN = 256, BK = 64;

// ---------------- per-token dynamic quantization ----------------
__global__ __launch_bounds__(256) void quant_kernel(const float* __restrict__ x,
                                                    signed char* __restrict__ xq,
                                                    float* __restrict__ xs) {
    const int token = blockIdx.x;
    const float4* row = (const float4*)(x + (size_t)token * K_DIM);
    const int t = threadIdx.x;
    float4 v[4];
    float m = 0.f;
#pragma unroll
    for (int i = 0; i < 4; ++i) {
        v[i] = row[t * 4 + i];
        m = fmaxf(m, fabsf(v[i].x));
        m = fmaxf(m, fabsf(v[i].y));
        m = fmaxf(m, fabsf(v[i].z));
        m = fmaxf(m, fabsf(v[i].w));
    }
#pragma unroll
    for (int d = 32; d > 0; d >>= 1) m = fmaxf(m, __shfl_xor(m, d));
    __shared__ float red[4];
    if ((t & 63) == 0) red[t >> 6] = m;
    __syncthreads();
    const float am = fmaxf(fmaxf(red[0], red[1]), fmaxf(red[2], red[3]));
    const float s = fmaxf(am, 1e-8f) * (1.0f / 127.0f);
    const float inv = 127.0f / fmaxf(am, 1e-8f);

    int pk[4];
#pragma unroll
    for (int i = 0; i < 4; ++i) {
        int q0 = (int)fminf(127.f, fmaxf(-127.f, rintf(v[i].x * inv)));
        int q1 = (int)fminf(127.f, fmaxf(-127.f, rintf(v[i].y * inv)));
        int q2 = (int)fminf(127.f, fmaxf(-127.f, rintf(v[i].z * inv)));
        int q3 = (int)fminf(127.f, fmaxf(-127.f, rintf(v[i].w * inv)));
        pk[i] = (q0 & 255) | ((q1 & 255) << 8) | ((q2 & 255) << 16) | (q3 << 24);
    }
    ((int4*)(xq + (size_t)token * K_DIM))[t] = make_int4(pk[0], pk[1], pk[2], pk[3]);
    if (t == 0) xs[token] = s;
}

// ---------------- weight repack: int32 -> packed int8 ----------------
__global__ __launch_bounds__(256) void repack_kernel(const int* __restrict__ w32,
                                                     int4* __restrict__ w8,
                                                     int n16) {
    const int idx = blockIdx.x * 256 + threadIdx.x;
    if (idx >= n16) return;
    const int4* src = (const int4*)w32 + (size_t)idx * 4;
    int4 a = src[0], b = src[1], c = src[2], d = src[3];
    int p0 = (a.x & 255) | ((a.y & 255) << 8) | ((a.z & 255) << 16) | (a.w << 24);
    int p1 = (b.x & 255) | ((b.y & 255) << 8) | ((b.z & 255) << 16) | (b.w << 24);
    int p2 = (c.x & 255) | ((c.y & 255) << 8) | ((c.z & 255) << 16) | (c.w << 24);
    int p3 = (d.x & 255) | ((d.y & 255) << 8) | ((d.z & 255) << 16) | (d.w << 24);
    w8[idx] = make_int4(p0, p1, p2, p3);
}

// ---- int8 MFMA GEMM: R23 body (single-barrier 3-buf rotation, counted
// ---- vmcnt(3), verified zero-conflict layout, LDS-transpose epilogue, NT
// ---- stores) with GROUP=4 + m204 bijective XCD swizzle: per-XCD A-slice
// ---- 2 MB -> comfortably L2-resident (GROUP=8's 4 MB was a marginal fit) ----
__global__ __launch_bounds__(512, 4) void gemm_kernel(const signed char* __restrict__ xq,
                                                      const signed char* __restrict__ w8,
                                                      const float* __restrict__ xs,
                                                      const float* __restrict__ scale,
                                                      const float* __restrict__ bias,
                                                      float* __restrict__ out,
                                                      int N) {
    __shared__ __align__(16) signed char smem_[73728];   // sA 24 KB | sB 48 KB; reused as epilogue scratch
#define sA (smem_)
#define sB (smem_ + 24576)

    const int tid = threadIdx.x;
    const int lane = tid & 63;
    const int wid = tid >> 6;          // 8 waves: 2(M) x 4(N)
    const int wm = wid >> 2;
    const int wn = wid & 3;

    // ---- 2-D supertiled block mapping, GROUP=4, bijective XCD chunking ----
    // gsize = 43*4 = 172 = 8*21+4 -> m204 form: XCDs 0-3 get 22 items, 4-7 get 21.
    const int GROUP = 4;
    int flat = blockIdx.y * gridDim.x + blockIdx.x;
    const int gsize = gridDim.x * GROUP;              // 172
    const int group = flat / gsize;
    const int r0 = flat % gsize;
    const int xcd = r0 & 7;
    const int j = r0 >> 3;
    const int w = (xcd < 4 ? xcd * 22 : 88 + (xcd - 4) * 21) + j;   // bijective 0..171
    const int bx = w / GROUP;
    const int by = group * GROUP + (w % GROUP);
    const int m0 = by * BM;
    const int n0 = bx * BN;

    v4i acc[4][4];
    const v4i vzero = {0, 0, 0, 0};
#pragma unroll
    for (int i = 0; i < 4; ++i)
#pragma unroll
        for (int jj = 0; jj < 4; ++jj) acc[i][jj] = vzero;

    // ---- staging sources (silicon-verified involution; LDS dest linear) ----
    const int srow = tid >> 3;
    const int s = (tid & 7) ^ (srow & 7);
    const signed char* srcA = xq + ((size_t)m0 + srow + (s >> 2) * 64) * K_DIM + (s & 3) * 16;
    const signed char* srcB = w8 + ((size_t)n0 + srow + (s >> 2) * 128) * K_DIM + (s & 3) * 16;

    auto stage = [&](int offA, int offB, unsigned int kb) {   // 3 issues: A, B-lo, B-hi
        __builtin_amdgcn_global_load_lds(
            (const __attribute__((address_space(1))) void*)(srcA + kb),
            (__attribute__((address_space(3))) void*)&sA[offA + wid * 1024], 16, 0, 0);
        __builtin_amdgcn_global_load_lds(
            (const __attribute__((address_space(1))) void*)(srcB + kb),
            (__attribute__((address_space(3))) void*)&sB[offB + wid * 1024], 16, 0, 0);
        __builtin_amdgcn_global_load_lds(
            (const __attribute__((address_space(1))) void*)(srcB + (size_t)64 * K_DIM + kb),
            (__attribute__((address_space(3))) void*)&sB[offB + 8192 + wid * 1024], 16, 0, 0);
    };

    // ---- read-side per-lane constants (silicon-verified zero-conflict) ----
    const int colA = ((wm * 4 + (lane >> 4)) ^ (lane & 7)) << 4;
    const int colB = (((wn >> 1) * 4 + (lane >> 4)) ^ (lane & 7)) << 4;
    const int rowA = (lane & 15) * 128;
    const int rowB = ((wn & 1) * 64 + (lane & 15)) * 128;

#define BODY(ORa, ORb, OSa, OSb, DOSTAGE, KB, VMSTR)                           \
    {                                                                          \
        asm volatile("" ::: "memory");          /* pin after prev barrier */   \
        if (DOSTAGE) stage((OSa), (OSb), (KB));                                \
        v4i a_[4], b_[4];                                                      \
        _Pragma("unroll") for (int mi = 0; mi < 4; ++mi)                       \
            a_[mi] = *(const v4i*)&sA[(ORa) + rowA + mi * 2048 + colA];        \
        _Pragma("unroll") for (int ni = 0; ni < 4; ++ni)                       \
            b_[ni] = *(const v4i*)&sB[(ORb) + rowB + ni * 2048 + colB];        \
        __builtin_amdgcn_s_setprio(1);                                         \
        _Pragma("unroll") for (int mi = 0; mi < 4; ++mi)                       \
            _Pragma("unroll") for (int ni = 0; ni < 4; ++ni)                   \
                acc[mi][ni] = __builtin_amdgcn_mfma_i32_16x16x64_i8(           \
                    a_[mi], b_[ni], acc[mi][ni], 0, 0, 0);                     \
        __builtin_amdgcn_s_setprio(0);                                         \
        asm volatile("" ::: "memory");          /* pin before barrier */       \
        asm volatile("s_waitcnt vmcnt(" VMSTR ")" ::: "memory");               \
        __builtin_amdgcn_s_barrier();                                          \
    }

    // ---- prologue: stage tiles 0,1 into bufs 0,1; publish tile 0 ----
    stage(0, 0, 0);
    stage(8192, 16384, BK);
    asm volatile("s_waitcnt vmcnt(3)" ::: "memory");   // tile 0 landed
    __builtin_amdgcn_s_barrier();

    // ---- main loop: bodies 0..59 (20 x 3, static offsets) ----
    unsigned int kb = 2 * BK;   // byte offset of tile staged at body 0
    for (int it = 0; it < 20; ++it) {
        BODY(0,     0,     16384, 32768, 1, kb,          "3");  // t=3it+0: rd buf0, st buf2
        BODY(8192,  16384, 0,     0,     1, kb + BK,     "3");  // t=3it+1: rd buf1, st buf0
        BODY(16384, 32768, 8192,  16384, 1, kb + 2 * BK, "3");  // t=3it+2: rd buf2, st buf1
        kb += 3 * BK;
    }

    // ---- tail: bodies 60,61 stage tiles 62,63; body 62 vmcnt(0); body 63 pure ----
    BODY(0,     0,     16384, 32768, 1, (unsigned int)(62 * BK), "3");  // body 60
    BODY(8192,  16384, 0,     0,     1, (unsigned int)(63 * BK), "3");  // body 61
    BODY(16384, 32768, 0,     0,     0, 0u,                      "0");  // body 62
    {   // body 63: reads buf0 (tile 63), MFMA only
        asm volatile("" ::: "memory");
        v4i a_[4], b_[4];
#pragma unroll
        for (int mi = 0; mi < 4; ++mi)
            a_[mi] = *(const v4i*)&sA[0 + rowA + mi * 2048 + colA];
#pragma unroll
        for (int ni = 0; ni < 4; ++ni)
            b_[ni] = *(const v4i*)&sB[0 + rowB + ni * 2048 + colB];
        __builtin_amdgcn_s_setprio(1);
#pragma unroll
        for (int mi = 0; mi < 4; ++mi)
#pragma unroll
            for (int ni = 0; ni < 4; ++ni)
                acc[mi][ni] = __builtin_amdgcn_mfma_i32_16x16x64_i8(
                    a_[mi], b_[ni], acc[mi][ni], 0, 0, 0);
        __builtin_amdgcn_s_setprio(0);
    }
#undef BODY

    // ---- LDS-transpose epilogue: full-cacheline f32x4 NON-TEMPORAL stores ----
    __syncthreads();   // all LDS reads of the K-loop complete before reuse
    float* ws_ = (float*)&smem_[wid * 8704];   // 32 rows x 68 floats per wave

    const int mrow0 = m0 + wm * 64 + ((lane >> 4) << 2);
    const int ncol0 = n0 + wn * 64 + (lane & 15);
    float xsv[4][4], scv[4], bsv[4];
#pragma unroll
    for (int mi = 0; mi < 4; ++mi)
#pragma unroll
        for (int r2 = 0; r2 < 4; ++r2) xsv[mi][r2] = xs[mrow0 + mi * 16 + r2];
#pragma unroll
    for (int ni = 0; ni < 4; ++ni) {
        scv[ni] = scale[ncol0 + ni * 16];
        bsv[ni] = bias[ncol0 + ni * 16];
    }

    const int mbase = m0 + wm * 64;
    const int nbase = n0 + wn * 64;
#pragma unroll
    for (int pass = 0; pass < 2; ++pass) {
#pragma unroll
        for (int mh = 0; mh < 2; ++mh) {
            const int mi = pass * 2 + mh;
#pragma unroll
            for (int ni = 0; ni < 4; ++ni) {
#pragma unroll
                for (int r2 = 0; r2 < 4; ++r2) {
                    const int lrow = mh * 16 + ((lane >> 4) << 2) + r2;
                    ws_[lrow * 68 + ni * 16 + (lane & 15)] =
                        (float)acc[mi][ni][r2] * xsv[mi][r2] * scv[ni] + bsv[ni];
                }
            }
        }
#pragma unroll
        for (int jj = 0; jj < 8; ++jj) {
            const int lrow = jj * 4 + (lane >> 4);
            const f32x4 v4 = *(const f32x4*)&ws_[lrow * 68 + (lane & 15) * 4];
            const int m = mbase + pass * 32 + lrow;
            __builtin_nontemporal_store(v4, (f32x4*)&out[(size_t)m * N + nbase + (lane & 15) * 4]);
        }
    }
#undef sA
#undef sB
}

extern "C" void kernel_launch(void* const* d_in, const int* in_sizes, int n_in,
                              void* d_out, int out_size, void* d_ws, size_t ws_size,
                              hipStream_t stream) {
    const float* x     = (const float*)d_in[0];
    const int*   w32   = (const int*)d_in[1];
    const float* scale = (const float*)d_in[2];
    const float* bias  = (const float*)d_in[3];
    float* out = (float*)d_out;

    const int M = in_sizes[0] / K_DIM;   // 8192
    const int N = in_sizes[2];           // 11008

    char* ws = (char*)d_ws;
    signed char* xq = (signed char*)ws;                                  // M*K
    float* xs = (float*)(ws + (size_t)M * K_DIM);                        // M floats
    signed char* w8 = (signed char*)(ws + (size_t)M * K_DIM + (size_t)M * sizeof(float));  // N*K

    quant_kernel<<<M, 256, 0, stream>>>(x, xq, xs);

    const int n16 = (N * K_DIM) / 16;
    repack_kernel<<<(n16 + 255) / 256, 256, 0, stream>>>(w32, (int4*)w8, n16);

    gemm_kernel<<<dim3(N / BN, M / BM), 512, 0, stream>>>(xq, w8, xs, scale, bias, out, N);
}